// Round 2
// baseline (548.318 us; speedup 1.0000x reference)
//
#include <hip/hip_runtime.h>

// Problem: B=4, C=64, H=128, W=416; corr 81 ch (dy,dx in [-4,4]); disp 192 ch (dx-96 in [-96,95])
// fp32 inputs/outputs (per reference dtype); compute via bf16 MFMA (harness compares with
// bf16-floored reference, threshold = 2% of absmax).
#define Wd 416
#define Hd 128
#define Cd 64
#define HWd 53248  // H*W

typedef __attribute__((ext_vector_type(8))) short short8;   // 8 bf16 MFMA fragment
typedef __attribute__((ext_vector_type(4))) float f32x4;    // MFMA accumulator

__device__ __forceinline__ float bf2f(unsigned short u) {
    unsigned int v = ((unsigned int)u) << 16;
    return __builtin_bit_cast(float, v);
}
__device__ __forceinline__ unsigned short f2bf(float f) {
    unsigned int u = __builtin_bit_cast(unsigned int, f);
    u += 0x7fffu + ((u >> 16) & 1u);   // round-to-nearest-even
    return (unsigned short)(u >> 16);
}

// ---------------------------------------------------------------------------
// Kernel 1: bilinear warp of x2 (fp32) by flow (fp32) -> x2wT bf16 in ws,
// layout [b][y][x][c] (c contiguous). 8 threads/pixel, 8 channels each.
// ---------------------------------------------------------------------------
__global__ __launch_bounds__(256) void warp_k(const float* __restrict__ x2,
                                              const float* __restrict__ flow,
                                              unsigned short* __restrict__ x2wT) {
    int gid = blockIdx.x * 256 + threadIdx.x;   // 4*128*416*8 threads exactly
    int j = gid & 7;          // channel octet
    int p = gid >> 3;         // pixel id
    int x = p % Wd;
    int t = p / Wd;
    int y = t & 127;
    int b = t >> 7;

    int fbase = ((b * 2) * Hd + y) * Wd + x;
    float fx = flow[fbase];            // x-offset = channel 0
    float fy = flow[fbase + HWd];      // y-offset = channel 1
    float gx = (float)x + fx;
    float gy = (float)y + fy;
    float fx0 = floorf(gx), fy0 = floorf(gy);
    float wx = gx - fx0, wy = gy - fy0;
    int x0 = (int)fx0, y0 = (int)fy0;
    bool vx0 = (unsigned)x0 < (unsigned)Wd, vx1 = (unsigned)(x0 + 1) < (unsigned)Wd;
    bool vy0 = (unsigned)y0 < (unsigned)Hd, vy1 = (unsigned)(y0 + 1) < (unsigned)Hd;
    int cx0 = min(max(x0, 0), Wd - 1), cx1 = min(max(x0 + 1, 0), Wd - 1);
    int cy0 = min(max(y0, 0), Hd - 1), cy1 = min(max(y0 + 1, 0), Hd - 1);
    float w00 = (1.f - wx) * (1.f - wy) * ((vx0 && vy0) ? 1.f : 0.f);
    float w01 = wx * (1.f - wy) * ((vx1 && vy0) ? 1.f : 0.f);
    float w10 = (1.f - wx) * wy * ((vx0 && vy1) ? 1.f : 0.f);
    float w11 = wx * wy * ((vx1 && vy1) ? 1.f : 0.f);
    int o00 = cy0 * Wd + cx0, o01 = cy0 * Wd + cx1;
    int o10 = cy1 * Wd + cx0, o11 = cy1 * Wd + cx1;

    const float* base = x2 + (long)(b * Cd + j * 8) * HWd;
    unsigned int res[4];
#pragma unroll
    for (int cc = 0; cc < 8; cc++) {
        const float* pc = base + cc * HWd;
        float v = w00 * pc[o00] + w01 * pc[o01] + w10 * pc[o10] + w11 * pc[o11];
        unsigned short h = f2bf(v);
        if (cc & 1) res[cc >> 1] |= ((unsigned int)h) << 16;
        else        res[cc >> 1] = h;
    }
    *(uint4*)(x2wT + ((long)p * Cd + j * 8)) = make_uint4(res[0], res[1], res[2], res[3]);
}

// ---------------------------------------------------------------------------
// Kernel 2: disp corr volume (192 channels), one block per (b, y).
// P[x,x'] = sum_c x1[c,x] * r1[c,x'];  out ch 81+d at (y,x) = lrelu(P[x, x+d-96]).
// MFMA 16x16x32_bf16 band matmul; d-chunks of 32 staged via LDS; fp32 copyout.
// ---------------------------------------------------------------------------
__global__ __launch_bounds__(512) void disp_k(const float* __restrict__ x1,
                                              const float* __restrict__ r1,
                                              float* __restrict__ out) {
    // A/B transposed [x][c] bf16, stride 72 (144B rows: 16B-aligned b128 frag reads)
    __shared__ unsigned short As[416 * 72];
    __shared__ unsigned short Bs[416 * 72];
    __shared__ unsigned short Ds[32 * 420];   // d-chunk result buffer

    int tid = threadIdx.x;
    int lane = tid & 63;
    int wv = tid >> 6;          // 8 waves
    int m = lane & 15;          // MFMA row/col within tile
    int q = lane >> 4;          // quad

    int bid = blockIdx.x;       // 512 blocks = 4b * 128y
    int b = bid >> 7;
    int y = bid & 127;

    const float* Arow = x1 + ((long)(b * Cd) * Hd + y) * Wd;
    const float* Brow = r1 + ((long)(b * Cd) * Hd + y) * Wd;

    // stage rows transposed + fp32->bf16: [c][x] global -> [x][c] LDS
    for (int idx = tid; idx < Cd * 104; idx += 512) {     // 104 = 416/4
        int c = idx / 104, x4 = (idx % 104) * 4;
        float4 va = *(const float4*)(Arow + (long)c * HWd + x4);
        float4 vb = *(const float4*)(Brow + (long)c * HWd + x4);
        As[(x4 + 0) * 72 + c] = f2bf(va.x);
        As[(x4 + 1) * 72 + c] = f2bf(va.y);
        As[(x4 + 2) * 72 + c] = f2bf(va.z);
        As[(x4 + 3) * 72 + c] = f2bf(va.w);
        Bs[(x4 + 0) * 72 + c] = f2bf(vb.x);
        Bs[(x4 + 1) * 72 + c] = f2bf(vb.y);
        Bs[(x4 + 2) * 72 + c] = f2bf(vb.z);
        Bs[(x4 + 3) * 72 + c] = f2bf(vb.w);
    }

    for (int k = 0; k < 6; k++) {            // d-chunk: d in [32k, 32k+32)
        // zero the chunk buffer (out-of-range x' stays 0; lrelu(0)=0 matches zero padding)
        for (int idx = tid; idx < 32 * 210; idx += 512) ((unsigned int*)Ds)[idx] = 0;
        __syncthreads();

        for (int i = wv; i < 26; i += 8) {   // A row tile (x in [16i,16i+16))
            const unsigned short* ap = &As[(16 * i + m) * 72];
            short8 a0 = *(const short8*)(ap + q * 8);
            short8 a1 = *(const short8*)(ap + 32 + q * 8);
#pragma unroll
            for (int gg = 0; gg < 3; gg++) { // col tiles jj = i + (2k-6..2k-4)
                int g = 2 * k - 6 + gg;
                int jj = i + g;
                if ((unsigned)jj >= 26u) continue;
                const unsigned short* bp = &Bs[(16 * jj + m) * 72];
                short8 b0 = *(const short8*)(bp + q * 8);
                short8 b1 = *(const short8*)(bp + 32 + q * 8);
                f32x4 acc = {0.f, 0.f, 0.f, 0.f};
                acc = __builtin_amdgcn_mfma_f32_16x16x32_bf16(a0, b0, acc, 0, 0, 0);
                acc = __builtin_amdgcn_mfma_f32_16x16x32_bf16(a1, b1, acc, 0, 0, 0);
                // lane holds P[x = 16i+4q+r][x' = 16jj+m]; d = x'-x+96
                int dbase = 16 * g + m - 4 * q + 96 - 32 * k;
                int xb = 16 * i + 4 * q;
#pragma unroll
                for (int r = 0; r < 4; r++) {
                    int dr = dbase - r;
                    if ((unsigned)dr < 32u) {
                        float v = acc[r];
                        v = (v >= 0.f) ? v : 0.1f * v;
                        Ds[dr * 420 + xb + r] = f2bf(v);
                    }
                }
            }
        }
        __syncthreads();

        // coalesced fp32 copyout of 32 channel-rows
        int chbase = ((b * 273 + 81 + 32 * k) * Hd + y) * Wd;
        for (int idx = tid; idx < 32 * Wd; idx += 512) {
            int dr = idx / Wd, xx = idx % Wd;
            out[chbase + dr * HWd + xx] = bf2f(Ds[dr * 420 + xx]);
        }
        __syncthreads();
    }
}

// ---------------------------------------------------------------------------
// Kernel 3: 81-channel corr volume, one block per (b, y-pair, x-half).
// Each x2w row staged ONCE per block (vs 9x for per-y blocks).
// ---------------------------------------------------------------------------
__global__ __launch_bounds__(512) void corr_k(const float* __restrict__ x1,
                                              const unsigned short* __restrict__ x2wT,
                                              float* __restrict__ out) {
    __shared__ unsigned short As[2 * 208 * 72];  // [yy][xl][c]
    __shared__ unsigned short Bs[224 * 72];      // [pl][c], pl = x'-xbase+4 (zero-padded halo)
    __shared__ unsigned short Cs[9 * 212];       // 9 dx channels x 208 x

    int tid = threadIdx.x;
    int lane = tid & 63;
    int wv = tid >> 6;
    int m = lane & 15;
    int q = lane >> 4;

    int bid = blockIdx.x;        // 512 = 4b * 64y2 * 2xh
    int b = bid & 3;
    int y2 = (bid >> 2) & 63;
    int xh = bid >> 8;
    int y0 = y2 * 2;
    int xbase = xh * 208;

    // stage x1 rows y0, y0+1 transposed + fp32->bf16
    for (int idx = tid; idx < 2 * Cd * 52; idx += 512) {   // 52 = 208/4
        int yy = idx / (Cd * 52);
        int r = idx % (Cd * 52);
        int c = r / 52, x4 = (r % 52) * 4;
        float4 va = *(const float4*)(x1 + ((long)(b * Cd + c) * Hd + y0 + yy) * Wd + xbase + x4);
        As[(yy * 208 + x4 + 0) * 72 + c] = f2bf(va.x);
        As[(yy * 208 + x4 + 1) * 72 + c] = f2bf(va.y);
        As[(yy * 208 + x4 + 2) * 72 + c] = f2bf(va.z);
        As[(yy * 208 + x4 + 3) * 72 + c] = f2bf(va.w);
    }

    for (int yp = 0; yp < 10; yp++) {        // x2w rows y0-4 .. y0+5, staged once each
        int yg = y0 - 4 + yp;
        bool yok = (unsigned)yg < (unsigned)Hd;
        __syncthreads();                      // protect Bs readers of previous iter (and As stage)
        for (int idx = tid; idx < 224 * 8; idx += 512) {
            int pl = idx >> 3, co = (idx & 7) * 8;
            int xg = xbase - 4 + pl;
            uint4 v = make_uint4(0, 0, 0, 0);
            if (yok && (unsigned)xg < (unsigned)Wd)
                v = *(const uint4*)(x2wT + (((long)(b * Hd + yg) * Wd + xg) * Cd + co));
            *(uint4*)&Bs[pl * 72 + co] = v;
        }
        __syncthreads();

        for (int yy = 0; yy < 2; yy++) {
            int dy = yp - 4 - yy;
            if (dy < -4 || dy > 4) continue;

            for (int it = wv; it < 13; it += 8) {
                const unsigned short* ap = &As[(yy * 208 + 16 * it + m) * 72];
                short8 a0 = *(const short8*)(ap + q * 8);
                short8 a1 = *(const short8*)(ap + 32 + q * 8);
#pragma unroll
                for (int dj = 0; dj < 2; dj++) {
                    int jt = it + dj;
                    const unsigned short* bp = &Bs[(16 * jt + m) * 72];
                    short8 b0 = *(const short8*)(bp + q * 8);
                    short8 b1 = *(const short8*)(bp + 32 + q * 8);
                    f32x4 acc = {0.f, 0.f, 0.f, 0.f};
                    acc = __builtin_amdgcn_mfma_f32_16x16x32_bf16(a0, b0, acc, 0, 0, 0);
                    acc = __builtin_amdgcn_mfma_f32_16x16x32_bf16(a1, b1, acc, 0, 0, 0);
                    // lane holds P[xl = 16it+4q+r][pl = 16jt+m]; dx+4 = pl - xl
                    int dbase = 16 * dj + m - 4 * q;
                    int xlb = 16 * it + 4 * q;
#pragma unroll
                    for (int r = 0; r < 4; r++) {
                        int dx4 = dbase - r;
                        if ((unsigned)dx4 <= 8u) {
                            float v = acc[r];
                            v = (v >= 0.f) ? v : 0.1f * v;
                            Cs[dx4 * 212 + xlb + r] = f2bf(v);
                        }
                    }
                }
            }
            __syncthreads();

            int ch = (dy + 4) * 9;
            for (int idx = tid; idx < 9 * 208; idx += 512) {
                int orow = idx / 208, xx = idx % 208;
                int off = ((b * 273 + ch + orow) * Hd + (y0 + yy)) * Wd + xbase + xx;
                out[off] = bf2f(Cs[orow * 212 + xx]);
            }
            __syncthreads();
        }
    }
}

extern "C" void kernel_launch(void* const* d_in, const int* in_sizes, int n_in,
                              void* d_out, int out_size, void* d_ws, size_t ws_size,
                              hipStream_t stream) {
    const float* x1 = (const float*)d_in[0];
    const float* x2 = (const float*)d_in[1];
    const float* r1 = (const float*)d_in[2];
    const float* fl = (const float*)d_in[3];
    float* out = (float*)d_out;
    unsigned short* x2wT = (unsigned short*)d_ws;   // 4*128*416*64 bf16 = 27.3 MB

    warp_k<<<6656, 256, 0, stream>>>(x2, fl, x2wT);        // 4*128*416*8/256
    disp_k<<<512, 512, 0, stream>>>(x1, r1, out);
    corr_k<<<512, 512, 0, stream>>>(x1, x2wT, out);
}

// Round 3
// 532.081 us; speedup vs baseline: 1.0305x; 1.0305x over previous
//
#include <hip/hip_runtime.h>

// Problem: B=4, C=64, H=128, W=416; corr 81 ch (dy,dx in [-4,4]); disp 192 ch (dx-96 in [-96,95])
// fp32 inputs/outputs; compute via bf16 MFMA (harness compares bf16-floored ref, thr=2% absmax).
#define Wd 416
#define Hd 128
#define Cd 64
#define HWd 53248  // H*W

typedef __attribute__((ext_vector_type(8))) short short8;   // 8 bf16 MFMA fragment
typedef __attribute__((ext_vector_type(4))) float f32x4;    // MFMA accumulator

__device__ __forceinline__ float bf2f(unsigned short u) {
    unsigned int v = ((unsigned int)u) << 16;
    return __builtin_bit_cast(float, v);
}
__device__ __forceinline__ unsigned short f2bf(float f) {
    unsigned int u = __builtin_bit_cast(unsigned int, f);
    u += 0x7fffu + ((u >> 16) & 1u);   // round-to-nearest-even
    return (unsigned short)(u >> 16);
}
__device__ __forceinline__ unsigned int pk2(float lo, float hi) {
    return (unsigned int)f2bf(lo) | ((unsigned int)f2bf(hi) << 16);
}

// ---------------------------------------------------------------------------
// Kernel 1: bilinear warp of x2 (fp32) by flow (fp32) -> x2wT bf16 in ws,
// layout [b][y][x][c] (c contiguous). 8 threads/pixel, 8 channels each.
// ---------------------------------------------------------------------------
__global__ __launch_bounds__(256) void warp_k(const float* __restrict__ x2,
                                              const float* __restrict__ flow,
                                              unsigned short* __restrict__ x2wT) {
    int gid = blockIdx.x * 256 + threadIdx.x;   // 4*128*416*8 threads exactly
    int j = gid & 7;          // channel octet
    int p = gid >> 3;         // pixel id
    int x = p % Wd;
    int t = p / Wd;
    int y = t & 127;
    int b = t >> 7;

    int fbase = ((b * 2) * Hd + y) * Wd + x;
    float fx = flow[fbase];            // x-offset = channel 0
    float fy = flow[fbase + HWd];      // y-offset = channel 1
    float gx = (float)x + fx;
    float gy = (float)y + fy;
    float fx0 = floorf(gx), fy0 = floorf(gy);
    float wx = gx - fx0, wy = gy - fy0;
    int x0 = (int)fx0, y0 = (int)fy0;
    bool vx0 = (unsigned)x0 < (unsigned)Wd, vx1 = (unsigned)(x0 + 1) < (unsigned)Wd;
    bool vy0 = (unsigned)y0 < (unsigned)Hd, vy1 = (unsigned)(y0 + 1) < (unsigned)Hd;
    int cx0 = min(max(x0, 0), Wd - 1), cx1 = min(max(x0 + 1, 0), Wd - 1);
    int cy0 = min(max(y0, 0), Hd - 1), cy1 = min(max(y0 + 1, 0), Hd - 1);
    float w00 = (1.f - wx) * (1.f - wy) * ((vx0 && vy0) ? 1.f : 0.f);
    float w01 = wx * (1.f - wy) * ((vx1 && vy0) ? 1.f : 0.f);
    float w10 = (1.f - wx) * wy * ((vx0 && vy1) ? 1.f : 0.f);
    float w11 = wx * wy * ((vx1 && vy1) ? 1.f : 0.f);
    int o00 = cy0 * Wd + cx0, o01 = cy0 * Wd + cx1;
    int o10 = cy1 * Wd + cx0, o11 = cy1 * Wd + cx1;

    const float* base = x2 + (long)(b * Cd + j * 8) * HWd;
    unsigned int res[4];
#pragma unroll
    for (int cc = 0; cc < 8; cc++) {
        const float* pc = base + cc * HWd;
        float v = w00 * pc[o00] + w01 * pc[o01] + w10 * pc[o10] + w11 * pc[o11];
        unsigned short h = f2bf(v);
        if (cc & 1) res[cc >> 1] |= ((unsigned int)h) << 16;
        else        res[cc >> 1] = h;
    }
    *(uint4*)(x2wT + ((long)p * Cd + j * 8)) = make_uint4(res[0], res[1], res[2], res[3]);
}

// ---------------------------------------------------------------------------
// Kernel 2: disp corr volume (192 channels), one block per (b, y).
// P[x,x'] = sum_c x1[c,x] * r1[c,x'];  out ch 81+d at (y,x) = lrelu(P[x, x+d-96]).
// Conflict-free staging: 1 thread = 1 x + 1 c-octet -> single ds_write_b128.
// ---------------------------------------------------------------------------
__global__ __launch_bounds__(512) void disp_k(const float* __restrict__ x1,
                                              const float* __restrict__ r1,
                                              float* __restrict__ out) {
    // A/B transposed [x][c] bf16, stride 72 (144B rows: 16B-aligned b128 frag reads)
    __shared__ unsigned short As[416 * 72];
    __shared__ unsigned short Bs[416 * 72];
    __shared__ unsigned short Ds[32 * 420];   // d-chunk result buffer

    int tid = threadIdx.x;
    int lane = tid & 63;
    int wv = tid >> 6;          // 8 waves
    int m = lane & 15;          // MFMA row/col within tile
    int q = lane >> 4;          // quad

    int bid = blockIdx.x;       // 512 blocks = 4b * 128y
    int b = bid >> 7;
    int y = bid & 127;

    const float* Arow = x1 + ((long)(b * Cd) * Hd + y) * Wd;
    const float* Brow = r1 + ((long)(b * Cd) * Hd + y) * Wd;

    // stage rows transposed + fp32->bf16. idx = octet*416 + x; lanes -> consecutive x
    // (coalesced b32 global, conflict-free ds_write_b128: bank start 4*(x+oc)%32).
    for (int idx = tid; idx < 8 * Wd; idx += 512) {     // 3328
        int x = idx % Wd;
        int oc = idx / Wd;
        const float* pa = Arow + (long)(oc * 8) * HWd + x;
        const float* pb = Brow + (long)(oc * 8) * HWd + x;
        unsigned int wa[4], wb[4];
#pragma unroll
        for (int e = 0; e < 4; e++) {
            wa[e] = pk2(pa[(2 * e) * HWd], pa[(2 * e + 1) * HWd]);
            wb[e] = pk2(pb[(2 * e) * HWd], pb[(2 * e + 1) * HWd]);
        }
        *(uint4*)&As[x * 72 + oc * 8] = make_uint4(wa[0], wa[1], wa[2], wa[3]);
        *(uint4*)&Bs[x * 72 + oc * 8] = make_uint4(wb[0], wb[1], wb[2], wb[3]);
    }

    for (int k = 0; k < 6; k++) {            // d-chunk: d in [32k, 32k+32)
        // zero the chunk buffer (out-of-range x' stays 0; lrelu(0)=0 matches zero padding)
        for (int idx = tid; idx < 32 * 210; idx += 512) ((unsigned int*)Ds)[idx] = 0;
        __syncthreads();

        for (int i = wv; i < 26; i += 8) {   // A row tile (x in [16i,16i+16))
            const unsigned short* ap = &As[(16 * i + m) * 72];
            short8 a0 = *(const short8*)(ap + q * 8);
            short8 a1 = *(const short8*)(ap + 32 + q * 8);
#pragma unroll
            for (int gg = 0; gg < 3; gg++) { // col tiles jj = i + (2k-6..2k-4)
                int g = 2 * k - 6 + gg;
                int jj = i + g;
                if ((unsigned)jj >= 26u) continue;
                const unsigned short* bp = &Bs[(16 * jj + m) * 72];
                short8 b0 = *(const short8*)(bp + q * 8);
                short8 b1 = *(const short8*)(bp + 32 + q * 8);
                f32x4 acc = {0.f, 0.f, 0.f, 0.f};
                acc = __builtin_amdgcn_mfma_f32_16x16x32_bf16(a0, b0, acc, 0, 0, 0);
                acc = __builtin_amdgcn_mfma_f32_16x16x32_bf16(a1, b1, acc, 0, 0, 0);
                // lane holds P[x = 16i+4q+r][x' = 16jj+m]; d = x'-x+96
                int dbase = 16 * g + m - 4 * q + 96 - 32 * k;
                int xb = 16 * i + 4 * q;
#pragma unroll
                for (int r = 0; r < 4; r++) {
                    int dr = dbase - r;
                    if ((unsigned)dr < 32u) {
                        float v = acc[r];
                        v = (v >= 0.f) ? v : 0.1f * v;
                        Ds[dr * 420 + xb + r] = f2bf(v);
                    }
                }
            }
        }
        __syncthreads();

        // coalesced fp32 copyout (float2) of 32 channel-rows
        int chbase = ((b * 273 + 81 + 32 * k) * Hd + y) * Wd;
        for (int idx = tid; idx < 32 * 208; idx += 512) {
            int dr = idx / 208, xw = (idx % 208) * 2;
            *(float2*)(out + chbase + dr * HWd + xw) =
                make_float2(bf2f(Ds[dr * 420 + xw]), bf2f(Ds[dr * 420 + xw + 1]));
        }
        __syncthreads();
    }
}

// ---------------------------------------------------------------------------
// Kernel 3: 81-channel corr volume, one block per (b, y-pair, x-half).
// Each x2w row staged ONCE per block (vs 9x for per-y blocks).
// ---------------------------------------------------------------------------
__global__ __launch_bounds__(512) void corr_k(const float* __restrict__ x1,
                                              const unsigned short* __restrict__ x2wT,
                                              float* __restrict__ out) {
    __shared__ unsigned short As[2 * 208 * 72];  // [yy][xl][c]
    __shared__ unsigned short Bs[224 * 72];      // [pl][c], pl = x'-xbase+4 (zero-padded halo)
    __shared__ unsigned short Cs[9 * 212];       // 9 dx channels x 208 x

    int tid = threadIdx.x;
    int lane = tid & 63;
    int wv = tid >> 6;
    int m = lane & 15;
    int q = lane >> 4;

    int bid = blockIdx.x;        // 512 = 4b * 64y2 * 2xh
    int b = bid & 3;
    int y2 = (bid >> 2) & 63;
    int xh = bid >> 8;
    int y0 = y2 * 2;
    int xbase = xh * 208;

    // stage x1 rows y0, y0+1 transposed + fp32->bf16; conflict-free b128 writes
    for (int idx = tid; idx < 2 * 8 * 208; idx += 512) {   // 3328
        int x = idx % 208;
        int t = idx / 208;       // 0..15
        int oc = t & 7, yy = t >> 3;
        const float* p = x1 + ((long)(b * Cd + oc * 8) * Hd + (y0 + yy)) * Wd + xbase + x;
        unsigned int w[4];
#pragma unroll
        for (int e = 0; e < 4; e++)
            w[e] = pk2(p[(2 * e) * HWd], p[(2 * e + 1) * HWd]);
        *(uint4*)&As[(yy * 208 + x) * 72 + oc * 8] = make_uint4(w[0], w[1], w[2], w[3]);
    }

    for (int yp = 0; yp < 10; yp++) {        // x2w rows y0-4 .. y0+5, staged once each
        int yg = y0 - 4 + yp;
        bool yok = (unsigned)yg < (unsigned)Hd;
        __syncthreads();                      // protect Bs readers of previous iter (and As stage)
        for (int idx = tid; idx < 224 * 8; idx += 512) {
            int pl = idx >> 3, co = (idx & 7) * 8;
            int xg = xbase - 4 + pl;
            uint4 v = make_uint4(0, 0, 0, 0);
            if (yok && (unsigned)xg < (unsigned)Wd)
                v = *(const uint4*)(x2wT + (((long)(b * Hd + yg) * Wd + xg) * Cd + co));
            *(uint4*)&Bs[pl * 72 + co] = v;
        }
        __syncthreads();

        for (int yy = 0; yy < 2; yy++) {
            int dy = yp - 4 - yy;
            if (dy < -4 || dy > 4) continue;

            for (int it = wv; it < 13; it += 8) {
                const unsigned short* ap = &As[(yy * 208 + 16 * it + m) * 72];
                short8 a0 = *(const short8*)(ap + q * 8);
                short8 a1 = *(const short8*)(ap + 32 + q * 8);
#pragma unroll
                for (int dj = 0; dj < 2; dj++) {
                    int jt = it + dj;
                    const unsigned short* bp = &Bs[(16 * jt + m) * 72];
                    short8 b0 = *(const short8*)(bp + q * 8);
                    short8 b1 = *(const short8*)(bp + 32 + q * 8);
                    f32x4 acc = {0.f, 0.f, 0.f, 0.f};
                    acc = __builtin_amdgcn_mfma_f32_16x16x32_bf16(a0, b0, acc, 0, 0, 0);
                    acc = __builtin_amdgcn_mfma_f32_16x16x32_bf16(a1, b1, acc, 0, 0, 0);
                    // lane holds P[xl = 16it+4q+r][pl = 16jt+m]; dx+4 = pl - xl
                    int dbase = 16 * dj + m - 4 * q;
                    int xlb = 16 * it + 4 * q;
#pragma unroll
                    for (int r = 0; r < 4; r++) {
                        int dx4 = dbase - r;
                        if ((unsigned)dx4 <= 8u) {
                            float v = acc[r];
                            v = (v >= 0.f) ? v : 0.1f * v;
                            Cs[dx4 * 212 + xlb + r] = f2bf(v);
                        }
                    }
                }
            }
            __syncthreads();

            int ch = (dy + 4) * 9;
            for (int idx = tid; idx < 9 * 104; idx += 512) {
                int orow = idx / 104, xw = (idx % 104) * 2;
                int off = ((b * 273 + ch + orow) * Hd + (y0 + yy)) * Wd + xbase + xw;
                *(float2*)(out + off) =
                    make_float2(bf2f(Cs[orow * 212 + xw]), bf2f(Cs[orow * 212 + xw + 1]));
            }
            __syncthreads();
        }
    }
}

extern "C" void kernel_launch(void* const* d_in, const int* in_sizes, int n_in,
                              void* d_out, int out_size, void* d_ws, size_t ws_size,
                              hipStream_t stream) {
    const float* x1 = (const float*)d_in[0];
    const float* x2 = (const float*)d_in[1];
    const float* r1 = (const float*)d_in[2];
    const float* fl = (const float*)d_in[3];
    float* out = (float*)d_out;
    unsigned short* x2wT = (unsigned short*)d_ws;   // 4*128*416*64 bf16 = 27.3 MB

    warp_k<<<6656, 256, 0, stream>>>(x2, fl, x2wT);        // 4*128*416*8/256
    disp_k<<<512, 512, 0, stream>>>(x1, r1, out);
    corr_k<<<512, 512, 0, stream>>>(x1, x2wT, out);
}